// Round 5
// baseline (849.488 us; speedup 1.0000x reference)
//
#include <hip/hip_runtime.h>

#define MM 128
#define NN 128
#define KK 128
#define NBATCH 4
#define ITERS 8
#define WIN 10
#define WSTRIDE 12
#define MNK (MM*NN*KK)

typedef _Float16 h2 __attribute__((ext_vector_type(2)));

__device__ __forceinline__ float wave_sum(float v) {
  v += __shfl_xor(v, 32, 64);
  v += __shfl_xor(v, 16, 64);
  v += __shfl_xor(v, 8, 64);
  v += __shfl_xor(v, 4, 64);
  v += __shfl_xor(v, 2, 64);
  v += __shfl_xor(v, 1, 64);
  return v;
}

// Round-5 = round-0's 294us kernel (the best structure measured: 128 thr,
// (1,2,2) micro-tile, single-buffered window, 2 barriers/iter, lowest DS
// work + conflicts) with ONE substantive change: conv weights packed as
// fp16 pairs (108 -> 54 regs). Unified-VGPR/AGPR occupancy model fitted to
// rounds 0-4: total regs = VGPR_Count + ~64 AGPR; R0 was 148 -> 2 waves/SIMD
// (30% occ). Halving the weight array brings total under 128 -> 4 waves/SIMD.
// launch_bounds(128,4) pins the cap; transients kept low (one weight float2
// converted at a time; per-i partial accumulators). S-compensation, bias,
// rscale, stats all stay fp32; absmax 0.5 with fp16 weights passed in R4.
__global__ __launch_bounds__(128, 4) void gridnet_kernel(
    const float* __restrict__ weight, const float* __restrict__ bias,
    const float* __restrict__ rscale, const float* __restrict__ x,
    float* __restrict__ out) {
  // window rows padded 10 -> 12 floats: float2-aligned and 2-way-bank-free
  __shared__ __align__(16) float Wl[WIN * WIN * WSTRIDE];
  __shared__ float red[8];

  const int t = threadIdx.x;
  const int r2 = t & 3, q2 = (t >> 2) & 3, p = t >> 4;
  const int r0 = r2 * 2, q0 = q2 * 2;

  // XCD-bijective swizzle (4096 % 8 == 0): adjacent-bk blocks (sharing 64B
  // weight/x cache lines) run on the same XCD's L2. FETCH 575->139 MB (R1).
  const int bx = ((blockIdx.x & 7) << 9) | ((int)blockIdx.x >> 3);
  const int bm = bx >> 8, bn = (bx >> 4) & 15, bk = bx & 15;

  const int gm0 = bm * 8, gn0 = bn * 8, gk0 = bk * 8;
  const int baseg = ((gm0 + p) * NN + (gn0 + q0)) * KK + (gk0 + r0);

  // packed per-thread weights: wpk[dq][o] = {w[dq][dr=0][o], w[dq][dr=1][o]}
  h2 wpk[2][27];
  float S[2][2] = {{0.f, 0.f}, {0.f, 0.f}};  // exact fp32 sums for -inv*mu*S
#pragma unroll
  for (int dq = 0; dq < 2; ++dq) {
#pragma unroll
    for (int o = 0; o < 27; ++o) {
      float2 wv = *(const float2*)(weight + o * MNK + baseg + dq * KK);
      wpk[dq][o] = h2{(_Float16)wv.x, (_Float16)wv.y};
      S[dq][0] += wv.x;
      S[dq][1] += wv.y;
    }
  }
  float bia[2][2], rsc[2][2];
#pragma unroll
  for (int dq = 0; dq < 2; ++dq) {
    float2 bv = *(const float2*)(bias + baseg + dq * KK);
    bia[dq][0] = bv.x; bia[dq][1] = bv.y;
    float2 rv = *(const float2*)(rscale + baseg + dq * KK);
    rsc[dq][0] = rv.x; rsc[dq][1] = rv.y;
  }

  for (int b = 0; b < NBATCH; ++b) {
    __syncthreads();  // protect Wl from previous batch's readers
    // ---- load 10^3 window (zero-padded at grid boundary) into LDS ----
    float sA = 0.f, sAq = 0.f, sH = 0.f, sHq = 0.f;
    for (int idx = t; idx < 1000; idx += 128) {
      int wp = idx / 100;
      int rem = idx - wp * 100;
      int wq = rem / 10;
      int wk = rem - wq * 10;
      int gm = gm0 - 1 + wp, gn = gn0 - 1 + wq, gk = gk0 - 1 + wk;
      float v = 0.0f;
      if ((unsigned)gm < 128u && (unsigned)gn < 128u && (unsigned)gk < 128u)
        v = x[((b * MM + gm) * NN + gn) * KK + gk];
      Wl[(wp * WIN + wq) * WSTRIDE + wk] = v;
      sA += v; sAq += v * v;
      // halo (window shell) never changes across iterations: fold once
      if (wp == 0 || wp == 9 || wq == 0 || wq == 9 || wk == 0 || wk == 9) {
        sH += v; sHq += v * v;
      }
    }
    sA = wave_sum(sA); sAq = wave_sum(sAq);
    sH = wave_sum(sH); sHq = wave_sum(sHq);
    if ((t & 63) == 0) {
      int wv_ = t >> 6;
      red[wv_ * 4 + 0] = sA; red[wv_ * 4 + 1] = sAq;
      red[wv_ * 4 + 2] = sH; red[wv_ * 4 + 3] = sHq;
    }
    __syncthreads();
    float totS = red[0] + red[4], totQ = red[1] + red[5];
    const float hS = red[2] + red[6], hQ = red[3] + red[7];

    // own interior acts in registers (kept in sync with LDS)
    float a[2][2];
#pragma unroll
    for (int dq = 0; dq < 2; ++dq)
#pragma unroll
      for (int dr = 0; dr < 2; ++dr)
        a[dq][dr] = Wl[((p + 1) * WIN + (q0 + dq + 1)) * WSTRIDE + (r0 + dr + 1)];

    float mu = totS * (1.0f / 1000.0f);
    float var = totQ * (1.0f / 1000.0f) - mu * mu;
    float inv = __builtin_amdgcn_rsqf(var + 1e-5f);

    for (int it = 0; it < ITERS; ++it) {
      // ---- locally-connected 3^3 conv on RAW acts (normalization folded) ----
      float acc[2][2] = {{0.f, 0.f}, {0.f, 0.f}};
#pragma unroll
      for (int i = 0; i < 3; ++i) {
        float v[4][4];
#pragma unroll
        for (int jj = 0; jj < 4; ++jj) {
          const float* bp = &Wl[((p + i) * WIN + (q0 + jj)) * WSTRIDE + r0];
          float2 u0 = *(const float2*)bp;
          float2 u1 = *(const float2*)(bp + 2);
          v[jj][0] = u0.x; v[jj][1] = u0.y; v[jj][2] = u1.x; v[jj][3] = u1.y;
        }
        // per-i partial accumulators: 3 independent 9-FMA chains per output
        // instead of one serial 27-FMA chain (latency-bound regime)
        float pacc[2][2] = {{0.f, 0.f}, {0.f, 0.f}};
#pragma unroll
        for (int j = 0; j < 3; ++j)
#pragma unroll
          for (int kc = 0; kc < 3; ++kc) {
            const int o = i * 9 + j * 3 + kc;  // compile-time
#pragma unroll
            for (int dq = 0; dq < 2; ++dq) {
              pacc[dq][0] += (float)wpk[dq][o].x * v[dq + j][kc];
              pacc[dq][1] += (float)wpk[dq][o].y * v[dq + j][kc + 1];
            }
          }
#pragma unroll
        for (int dq = 0; dq < 2; ++dq) {
          acc[dq][0] += pacc[dq][0];
          acc[dq][1] += pacc[dq][1];
        }
      }
      // acc_final = bias + inv*(conv_raw) - inv*mu*(sum of 27 weights)
      const float im = inv * mu;
#pragma unroll
      for (int dq = 0; dq < 2; ++dq)
#pragma unroll
        for (int dr = 0; dr < 2; ++dr) {
          float z = bia[dq][dr] + inv * acc[dq][dr] - im * S[dq][dr];
          float e = __expf(-z);
          float sg = __builtin_amdgcn_rcpf(1.0f + e);  // sigmoid(z)
          a[dq][dr] += rsc[dq][dr] * (z * sg);          // residual silu
        }
      if (it < ITERS - 1) {
        __syncthreads();  // all conv reads done before anyone writes
#pragma unroll
        for (int dq = 0; dq < 2; ++dq)
#pragma unroll
          for (int dr = 0; dr < 2; ++dr)
            Wl[((p + 1) * WIN + (q0 + dq + 1)) * WSTRIDE + (r0 + dr + 1)] = a[dq][dr];
        float ls = a[0][0] + a[0][1] + a[1][0] + a[1][1];
        float lq = a[0][0] * a[0][0] + a[0][1] * a[0][1] +
                   a[1][0] * a[1][0] + a[1][1] * a[1][1];
        ls = wave_sum(ls); lq = wave_sum(lq);
        if ((t & 63) == 0) { red[(t >> 6) * 2 + 0] = ls; red[(t >> 6) * 2 + 1] = lq; }
        __syncthreads();  // partials ready AND writes visible for next iter
        float tS = red[0] + red[2] + hS;
        float tQ = red[1] + red[3] + hQ;
        mu = tS * (1.0f / 1000.0f);
        var = tQ * (1.0f / 1000.0f) - mu * mu;
        inv = __builtin_amdgcn_rsqf(var + 1e-5f);
      }
    }
    // ---- write final interior from registers ----
    const int baseo = ((b * MM + gm0 + p) * NN + (gn0 + q0)) * KK + (gk0 + r0);
#pragma unroll
    for (int dq = 0; dq < 2; ++dq) {
      float2 ov; ov.x = a[dq][0]; ov.y = a[dq][1];
      *(float2*)(out + baseo + dq * KK) = ov;
    }
  }
}

extern "C" void kernel_launch(void* const* d_in, const int* in_sizes, int n_in,
                              void* d_out, int out_size, void* d_ws, size_t ws_size,
                              hipStream_t stream) {
  const float* weight = (const float*)d_in[0];
  const float* bias   = (const float*)d_in[1];
  const float* rscale = (const float*)d_in[2];
  const float* x      = (const float*)d_in[3];
  // d_in[4] = inner_iterations (8), d_in[5] = block_size (8): fixed by harness
  float* out = (float*)d_out;
  gridnet_kernel<<<dim3(16 * 16 * 16), dim3(128), 0, stream>>>(
      weight, bias, rscale, x, out);
}

// Round 7
// 666.231 us; speedup vs baseline: 1.2751x; 1.2751x over previous
//
#include <hip/hip_runtime.h>

#define MM 128
#define NN 128
#define KK 128
#define NBATCH 4
#define ITERS 8
#define WIN 10
#define WSTRIDE 12
#define MNK (MM*NN*KK)

typedef _Float16 h2 __attribute__((ext_vector_type(2)));

// full 64-lane butterfly on a (sum, sumsq) pair; all lanes end with totals
__device__ __forceinline__ void bfly2(float& s, float& q) {
  s += __shfl_xor(s, 32, 64); q += __shfl_xor(q, 32, 64);
  s += __shfl_xor(s, 16, 64); q += __shfl_xor(q, 16, 64);
  s += __shfl_xor(s, 8, 64);  q += __shfl_xor(q, 8, 64);
  s += __shfl_xor(s, 4, 64);  q += __shfl_xor(q, 4, 64);
  s += __shfl_xor(s, 2, 64);  q += __shfl_xor(q, 2, 64);
  s += __shfl_xor(s, 1, 64);  q += __shfl_xor(q, 1, 64);
}

// Round-7 = round-6 (single-wave block) + the required memory fences.
// R6 raced: cross-lane LDS traffic with NO fence lets the COMPILER hoist
// next-iter ds_reads above this-iter ds_writes (per-thread alias analysis
// can't see cross-lane deps) -> absmax 44.75. The hardware-ordering argument
// was right; the source-level one was wrong. With launch_bounds(64,..) the
// backend knows the workgroup is one wave and lowers __syncthreads() to a
// wave-level fence (no inter-wave rendezvous cost), so we keep all of R6's
// structural wins: zero 2-wave barrier rendezvous, stats as a pure register
// butterfly (no LDS partial round-trip), (2,2,2) tile = 4 ds_read/output
// (vs 6 in R0) and 8 independent FMA chains of ILP, fp16-packed weights
// (216 vals -> 108 regs; absmax 0.5 vs threshold 2.11 -- ample margin).
__global__ __launch_bounds__(64, 2) void gridnet_kernel(
    const float* __restrict__ weight, const float* __restrict__ bias,
    const float* __restrict__ rscale, const float* __restrict__ x,
    float* __restrict__ out) {
  // rows padded 10 -> 12 floats: b64-aligned reads at even cols, 2-way-free
  __shared__ __align__(16) float Wl[WIN * WIN * WSTRIDE];

  const int l = threadIdx.x;
  const int ri = l & 3, qi = (l >> 2) & 3, pi = l >> 4;
  const int p0 = pi * 2, q0 = qi * 2, r0 = ri * 2;  // micro-tile origin

  // XCD-bijective swizzle (4096 % 8 == 0): adjacent-bk blocks (sharing 64B
  // weight/x cache lines) run on the same XCD's L2. FETCH 575->139 MB (R1).
  const int bx = ((blockIdx.x & 7) << 9) | ((int)blockIdx.x >> 3);
  const int bm = bx >> 8, bn = (bx >> 4) & 15, bk = bx & 15;
  const int gm0 = bm * 8, gn0 = bn * 8, gk0 = bk * 8;

  // packed weights: wpk[dp][dq][o] = {w(dp,dq,dr=0,o), w(dp,dq,dr=1,o)}
  // 2*2*27 = 108 h2 regs for 216 values. S compensation stays exact fp32.
  h2 wpk[2][2][27];
  float S[2][2][2];
#pragma unroll
  for (int dp = 0; dp < 2; ++dp)
#pragma unroll
    for (int dq = 0; dq < 2; ++dq) {
      const int basew = ((gm0 + p0 + dp) * NN + (gn0 + q0 + dq)) * KK + (gk0 + r0);
      float s0 = 0.f, s1 = 0.f;
#pragma unroll
      for (int o = 0; o < 27; ++o) {
        float2 wv = *(const float2*)(weight + o * MNK + basew);
        wpk[dp][dq][o] = h2{(_Float16)wv.x, (_Float16)wv.y};
        s0 += wv.x; s1 += wv.y;
      }
      S[dp][dq][0] = s0; S[dp][dq][1] = s1;
    }
  float bia[2][2][2], rsc[2][2][2];
#pragma unroll
  for (int dp = 0; dp < 2; ++dp)
#pragma unroll
    for (int dq = 0; dq < 2; ++dq) {
      const int baseb = ((gm0 + p0 + dp) * NN + (gn0 + q0 + dq)) * KK + (gk0 + r0);
      float2 bv = *(const float2*)(bias + baseb);
      bia[dp][dq][0] = bv.x; bia[dp][dq][1] = bv.y;
      float2 rv = *(const float2*)(rscale + baseb);
      rsc[dp][dq][0] = rv.x; rsc[dp][dq][1] = rv.y;
    }

  for (int b = 0; b < NBATCH; ++b) {
    __syncthreads();  // WAR fence: window load below vs prev batch's reads
                      // (single-wave WG: lowers to a wave-level fence)
    // ---- load 10^3 window (zero-padded at boundary) into LDS ----
    float sA = 0.f, sAq = 0.f, sH = 0.f, sHq = 0.f;
    for (int idx = l; idx < 1000; idx += 64) {
      int wp = idx / 100;
      int rem = idx - wp * 100;
      int wq = rem / 10;
      int wk = rem - wq * 10;
      int gm = gm0 - 1 + wp, gn = gn0 - 1 + wq, gk = gk0 - 1 + wk;
      float v = 0.0f;
      if ((unsigned)gm < 128u && (unsigned)gn < 128u && (unsigned)gk < 128u)
        v = x[((b * MM + gm) * NN + gn) * KK + gk];
      Wl[(wp * WIN + wq) * WSTRIDE + wk] = v;
      sA += v; sAq += v * v;
      // halo (window shell) never changes across iterations: fold once
      if (wp == 0 || wp == 9 || wq == 0 || wq == 9 || wk == 0 || wk == 9) {
        sH += v; sHq += v * v;
      }
    }
    __syncthreads();  // RAW fence: lanes read other lanes' window writes
    bfly2(sA, sAq);  // all lanes: full-window totals
    bfly2(sH, sHq);  // all lanes: halo totals (static across iters)
    const float hS = sH, hQ = sHq;

    // own interior acts in registers (kept in sync with LDS)
    float a[2][2][2];
#pragma unroll
    for (int dp = 0; dp < 2; ++dp)
#pragma unroll
      for (int dq = 0; dq < 2; ++dq)
#pragma unroll
        for (int dr = 0; dr < 2; ++dr)
          a[dp][dq][dr] =
              Wl[((p0 + dp + 1) * WIN + (q0 + dq + 1)) * WSTRIDE + (r0 + dr + 1)];

    float mu = sA * (1.0f / 1000.0f);
    float var = sAq * (1.0f / 1000.0f) - mu * mu;
    float inv = __builtin_amdgcn_rsqf(var + 1e-5f);

    for (int it = 0; it < ITERS; ++it) {
      // ---- 3^3 locally-connected conv on RAW acts (norm folded into
      // epilogue); neighborhood = 4x4x4 window cube at (p0,q0,r0) ----
      float acc[2][2][2] = {{{0.f,0.f},{0.f,0.f}},{{0.f,0.f},{0.f,0.f}}};
#pragma unroll
      for (int i = 0; i < 4; ++i) {
        // plane p0+i: rows q0..q0+3, cols r0..r0+3 (b64-aligned: r0 even)
        float v[4][4];
#pragma unroll
        for (int j = 0; j < 4; ++j) {
          const float* bp = &Wl[((p0 + i) * WIN + (q0 + j)) * WSTRIDE + r0];
          float2 u0 = *(const float2*)bp;
          float2 u1 = *(const float2*)(bp + 2);
          v[j][0] = u0.x; v[j][1] = u0.y; v[j][2] = u1.x; v[j][3] = u1.y;
        }
#pragma unroll
        for (int dp = 0; dp < 2; ++dp) {
          const int ii = i - dp;          // weight plane index
          if (ii < 0 || ii > 2) continue; // compile-time pruned
#pragma unroll
          for (int dq = 0; dq < 2; ++dq)
#pragma unroll
            for (int j2 = 0; j2 < 3; ++j2)
#pragma unroll
              for (int kc = 0; kc < 3; ++kc) {
                const int o = ii * 9 + j2 * 3 + kc;  // compile-time
                acc[dp][dq][0] += (float)wpk[dp][dq][o].x * v[dq + j2][kc];
                acc[dp][dq][1] += (float)wpk[dp][dq][o].y * v[dq + j2][kc + 1];
              }
        }
      }
      // acc_final = bias + inv*conv_raw - inv*mu*(sum of 27 weights)
      const float im = inv * mu;
#pragma unroll
      for (int dp = 0; dp < 2; ++dp)
#pragma unroll
        for (int dq = 0; dq < 2; ++dq)
#pragma unroll
          for (int dr = 0; dr < 2; ++dr) {
            float z = bia[dp][dq][dr] + inv * acc[dp][dq][dr] - im * S[dp][dq][dr];
            float e = __expf(-z);
            float sg = __builtin_amdgcn_rcpf(1.0f + e);  // sigmoid(z)
            a[dp][dq][dr] += rsc[dp][dq][dr] * (z * sg);  // residual silu
          }
      if (it < ITERS - 1) {
        // write own interior back (values data-depend on this iter's reads,
        // so reads-before-writes is enforced by dataflow)
#pragma unroll
        for (int dp = 0; dp < 2; ++dp)
#pragma unroll
          for (int dq = 0; dq < 2; ++dq) {
            const int rb = ((p0 + dp + 1) * WIN + (q0 + dq + 1)) * WSTRIDE + r0;
            Wl[rb + 1] = a[dp][dq][0];
            Wl[rb + 2] = a[dp][dq][1];
          }
        __syncthreads();  // RAW fence: next iter's conv reads see the writes
        // next iteration's stats: pure register butterfly, no LDS round-trip
        float ls = 0.f, lq = 0.f;
#pragma unroll
        for (int dp = 0; dp < 2; ++dp)
#pragma unroll
          for (int dq = 0; dq < 2; ++dq)
#pragma unroll
            for (int dr = 0; dr < 2; ++dr) {
              ls += a[dp][dq][dr];
              lq += a[dp][dq][dr] * a[dp][dq][dr];
            }
        bfly2(ls, lq);
        const float tS = ls + hS;
        const float tQ = lq + hQ;
        mu = tS * (1.0f / 1000.0f);
        var = tQ * (1.0f / 1000.0f) - mu * mu;
        inv = __builtin_amdgcn_rsqf(var + 1e-5f);
      }
    }
    // ---- write final interior from registers ----
#pragma unroll
    for (int dp = 0; dp < 2; ++dp)
#pragma unroll
      for (int dq = 0; dq < 2; ++dq) {
        const int baseo =
            ((b * MM + gm0 + p0 + dp) * NN + (gn0 + q0 + dq)) * KK + (gk0 + r0);
        float2 ov; ov.x = a[dp][dq][0]; ov.y = a[dp][dq][1];
        *(float2*)(out + baseo) = ov;
      }
  }
}

extern "C" void kernel_launch(void* const* d_in, const int* in_sizes, int n_in,
                              void* d_out, int out_size, void* d_ws, size_t ws_size,
                              hipStream_t stream) {
  const float* weight = (const float*)d_in[0];
  const float* bias   = (const float*)d_in[1];
  const float* rscale = (const float*)d_in[2];
  const float* x      = (const float*)d_in[3];
  // d_in[4] = inner_iterations (8), d_in[5] = block_size (8): fixed by harness
  float* out = (float*)d_out;
  gridnet_kernel<<<dim3(16 * 16 * 16), dim3(64), 0, stream>>>(
      weight, bias, rscale, x, out);
}